// Round 7
// baseline (72.721 us; speedup 1.0000x reference)
//
#include <hip/hip_runtime.h>
#include <math.h>

// IntraVolume_Attention collapses algebraically:
//   scores[b,v,f,g] = c * x[b,v,f] * x[b,v,g],  c = dot(w_q,w_k)/sqrt(128)
//   out[b,v,d] = w_v[d] * mean_f( softmax_weighted_mean_g(x) with logits c*x_f*x_g )
//
// R6 landed exactly on the trans-pipe saturation time (1024 wave-exps/SIMD
// x 16 cyc = 6.8 us ~= measured 6.9): v_exp_f32 runs in a quarter-rate unit
// that OVERLAPS VALU from other waves (hyp O). R7: split exps 50/50 between
// the trans pipe and a packed-VALU polynomial exp2 (magic-add round +
// degree-5 Taylor + exponent bit-add). Balanced load: trans 8.2k cyc,
// VALU 9.7k cyc -> kernel ~4 us. If trans actually blocks issue (hyp S),
// this regresses ~1 us and decodes the pipe model instead.

#if __has_builtin(__builtin_amdgcn_exp2f)
#define EXP2(x) __builtin_amdgcn_exp2f(x)   // raw v_exp_f32
#else
#define EXP2(x) exp2f(x)
#endif

typedef float v2f __attribute__((ext_vector_type(2)));
typedef int   v2i __attribute__((ext_vector_type(2)));

#define F_DIM 512

// Packed exp2 for t <= 0 (softmax args), VALU-only (no trans pipe).
// Magic-add round-to-nearest, degree-5 Taylor for 2^r on [-0.5,0.5],
// 2^n via integer add into the exponent field.
__device__ __forceinline__ v2f exp2_poly2(v2f t) {
    const v2f LO    = { -126.0f, -126.0f };
    const v2f MAGIC = { 12582912.0f, 12582912.0f };   // 1.5 * 2^23
    t = __builtin_elementwise_max(t, LO);
    const v2f S = t + MAGIC;          // mantissa of S holds round(t)
    const v2f n = S - MAGIC;
    const v2f r = t - n;              // exact, r in [-0.5, 0.5]
    v2f p = { 0.0013333558f, 0.0013333558f };                       // ln2^5/5!
    const v2f c4 = { 0.0096181291f, 0.0096181291f };
    const v2f c3 = { 0.0555041087f, 0.0555041087f };
    const v2f c2 = { 0.2402265069f, 0.2402265069f };
    const v2f c1 = { 0.6931471806f, 0.6931471806f };
    const v2f c0 = { 1.0f, 1.0f };
    p = __builtin_elementwise_fma(r, p, c4);
    p = __builtin_elementwise_fma(r, p, c3);
    p = __builtin_elementwise_fma(r, p, c2);
    p = __builtin_elementwise_fma(r, p, c1);
    p = __builtin_elementwise_fma(r, p, c0);
    const v2i pb = __builtin_bit_cast(v2i, p);
    const v2i Sb = __builtin_bit_cast(v2i, S);
    const v2i ib = pb + (Sb << 23);   // (0x400000+n)<<23 == n<<23 (mod 2^32)
    return __builtin_bit_cast(v2f, ib);
}

__global__ __launch_bounds__(1024) void intravol_attn(
    const float* __restrict__ x,    // [256, 512]
    const float* __restrict__ wq,   // [128]
    const float* __restrict__ wk,   // [128]
    const float* __restrict__ wv,   // [128]
    float* __restrict__ out)        // [256, 128]
{
    __shared__ __align__(16) float xs[F_DIM];
    __shared__ __align__(8) float pden[4][F_DIM];  // [g-slice][f]
    __shared__ __align__(8) float pnum[4][F_DIM];
    __shared__ float wmax[8], wmin[8], wsum[8];
    __shared__ float s_c, s_xmax, s_xmin;

    const int tid  = threadIdx.x;
    const int lane = tid & 63;
    const int wave = tid >> 6;
    const int row  = blockIdx.x;

    // Stage the row (threads 0..511); waves 0..7 reduce max/min, wave 8
    // concurrently computes c = dot(wq,wk)/sqrt(128).
    float xv = 0.0f;
    if (tid < F_DIM) { xv = x[row * F_DIM + tid]; xs[tid] = xv; }
    if (wave < 8) {
        float mx = xv, mn = xv;
        for (int o = 32; o > 0; o >>= 1) {
            mx = fmaxf(mx, __shfl_down(mx, o));
            mn = fminf(mn, __shfl_down(mn, o));
        }
        if (lane == 0) { wmax[wave] = mx; wmin[wave] = mn; }
    } else if (wave == 8) {
        float d = wq[lane] * wk[lane] + wq[lane + 64] * wk[lane + 64];
        for (int o = 32; o > 0; o >>= 1) d += __shfl_down(d, o);
        if (lane == 0) s_c = d * 0.08838834764831845f;
    }
    __syncthreads();
    if (tid == 0) {
        float M = wmax[0], m_ = wmin[0];
        #pragma unroll
        for (int i = 1; i < 8; ++i) { M = fmaxf(M, wmax[i]); m_ = fminf(m_, wmin[i]); }
        s_xmax = M; s_xmin = m_;
    }
    __syncthreads();

    // Thread = (f-pair, 128-g slice). Slice uniform per wave -> LDS broadcast.
    const float LOG2E = 1.4426950408889634f;
    const int f0 = (tid & 255) << 1;    // even f
    const int sl = tid >> 8;            // g-slice 0..3

    const float a0 = s_c * xs[f0]     * LOG2E;
    const float a1 = s_c * xs[f0 + 1] * LOG2E;
    v2f a2  = { a0, a1 };
    v2f bb  = { -((a0 >= 0.0f) ? a0 * s_xmax : a0 * s_xmin),
                -((a1 >= 0.0f) ? a1 * s_xmax : a1 * s_xmin) };
    v2f den = { 0.0f, 0.0f };
    v2f num = { 0.0f, 0.0f };

    const float4* xs4 = (const float4*)&xs[sl << 7];
    #pragma unroll 8
    for (int i = 0; i < 32; ++i) {      // 32 broadcast ds_read_b128 = 128 g
        const float4 v = xs4[i];
        // g0, g1 -> trans pipe (v_exp_f32); g2, g3 -> VALU polynomial.
        {
            const v2f xg2 = { v.x, v.x };
            const v2f arg = __builtin_elementwise_fma(a2, xg2, bb);
            const v2f e   = { EXP2(arg.x), EXP2(arg.y) };
            den += e; num = __builtin_elementwise_fma(e, xg2, num);
        }
        {
            const v2f xg2 = { v.y, v.y };
            const v2f arg = __builtin_elementwise_fma(a2, xg2, bb);
            const v2f e   = { EXP2(arg.x), EXP2(arg.y) };
            den += e; num = __builtin_elementwise_fma(e, xg2, num);
        }
        {
            const v2f xg2 = { v.z, v.z };
            const v2f arg = __builtin_elementwise_fma(a2, xg2, bb);
            const v2f e   = exp2_poly2(arg);
            den += e; num = __builtin_elementwise_fma(e, xg2, num);
        }
        {
            const v2f xg2 = { v.w, v.w };
            const v2f arg = __builtin_elementwise_fma(a2, xg2, bb);
            const v2f e   = exp2_poly2(arg);
            den += e; num = __builtin_elementwise_fma(e, xg2, num);
        }
    }
    *(v2f*)&pden[sl][f0] = den;
    *(v2f*)&pnum[sl][f0] = num;
    __syncthreads();

    // Combine 4 slices per f, s_f = num/den, block-sum over 512 f's.
    float sf = 0.0f;
    if (tid < F_DIM) {
        float D = 0.0f, N = 0.0f;
        #pragma unroll
        for (int s = 0; s < 4; ++s) { D += pden[s][tid]; N += pnum[s][tid]; }
        sf = N / D;
    }
    float t = sf;
    for (int o = 32; o > 0; o >>= 1) t += __shfl_down(t, o);
    if (lane == 0 && wave < 8) wsum[wave] = t;
    __syncthreads();

    if (tid < 128) {
        float total = 0.0f;
        #pragma unroll
        for (int i = 0; i < 8; ++i) total += wsum[i];
        out[row * 128 + tid] = total * (1.0f / (float)F_DIM) * wv[tid];
    }
}

extern "C" void kernel_launch(void* const* d_in, const int* in_sizes, int n_in,
                              void* d_out, int out_size, void* d_ws, size_t ws_size,
                              hipStream_t stream) {
    const float* x  = (const float*)d_in[0];  // [8,32,512]
    const float* wq = (const float*)d_in[1];  // [1,128]
    const float* wk = (const float*)d_in[2];  // [1,128]
    const float* wv = (const float*)d_in[3];  // [1,128]
    float* out = (float*)d_out;               // [8,32,128]

    intravol_attn<<<256, 1024, 0, stream>>>(x, wq, wk, wv, out);
}

// Round 8
// 67.440 us; speedup vs baseline: 1.0783x; 1.0783x over previous
//
#include <hip/hip_runtime.h>
#include <math.h>

// IntraVolume_Attention collapses algebraically:
//   scores[b,v,f,g] = c * x[b,v,f] * x[b,v,g],  c = dot(w_q,w_k)/sqrt(128)
//   out[b,v,d] = w_v[d] * mean_f( softmax_weighted_mean_g(x) with logits c*x_f*x_g )
//
// Measured model (R1-R7): harness re-poison floor ~59-60 us (268 MB d_ws fill
// at 84% HBM peak — untouchable). Kernel is bound by the transcendental pipe:
// ~16 lanes/cyc/CU -> 67M exps = 6.8 us, which R6 hit. R7 proved moving exps
// to a VALU polynomial is a pure loss (no packed-int ops, no trans/VALU
// co-issue). R8: delete all deletable overhead — max-subtraction removed
// (identity for softmax; logits |c*x_f*x_g| <~ 50 << 88-nat overflow; den>=1
// since max logit >= 0), so no max/min reduction, no serial combine, one
// barrier fewer; split accumulators for ILP. Loop stays pk_mul + 2 exp +
// pk_add + pk_fma per f-pair element.

#if __has_builtin(__builtin_amdgcn_exp2f)
#define EXP2(x) __builtin_amdgcn_exp2f(x)   // raw v_exp_f32
#else
#define EXP2(x) exp2f(x)
#endif

typedef float v2f __attribute__((ext_vector_type(2)));

#define F_DIM 512

__global__ __launch_bounds__(1024) void intravol_attn(
    const float* __restrict__ x,    // [256, 512]
    const float* __restrict__ wq,   // [128]
    const float* __restrict__ wk,   // [128]
    const float* __restrict__ wv,   // [128]
    float* __restrict__ out)        // [256, 128]
{
    __shared__ __align__(16) float xs[F_DIM];
    __shared__ __align__(8) float pden[4][F_DIM];  // [g-slice][f]
    __shared__ __align__(8) float pnum[4][F_DIM];
    __shared__ float wsum[8];
    __shared__ float s_c;

    const int tid  = threadIdx.x;
    const int lane = tid & 63;
    const int wave = tid >> 6;
    const int row  = blockIdx.x;

    // Prologue: stage the row; wave 8 computes c = dot(wq,wk)/sqrt(128)*log2e.
    if (tid < F_DIM) xs[tid] = x[row * F_DIM + tid];
    if (wave == 8) {
        float d = wq[lane] * wk[lane] + wq[lane + 64] * wk[lane + 64];
        for (int o = 32; o > 0; o >>= 1) d += __shfl_down(d, o);
        if (lane == 0) s_c = d * (0.08838834764831845f * 1.4426950408889634f);
    }
    __syncthreads();

    // Thread = (f-pair, 128-g slice). Slice uniform per wave -> LDS broadcast.
    const int f0 = (tid & 255) << 1;    // even f
    const int sl = tid >> 8;            // g-slice 0..3

    const float cl = s_c;
    v2f a2 = { cl * xs[f0], cl * xs[f0 + 1] };
    v2f den0 = { 0.0f, 0.0f }, den1 = { 0.0f, 0.0f };
    v2f num0 = { 0.0f, 0.0f }, num1 = { 0.0f, 0.0f };

    const float4* xs4 = (const float4*)&xs[sl << 7];
    #pragma unroll 8
    for (int i = 0; i < 32; ++i) {      // 32 broadcast ds_read_b128 = 128 g
        const float4 v = xs4[i];
        {
            const v2f xg2 = { v.x, v.x };
            const v2f arg = a2 * xg2;                          // v_pk_mul_f32
            const v2f e   = { EXP2(arg.x), EXP2(arg.y) };
            den0 += e; num0 = __builtin_elementwise_fma(e, xg2, num0);
        }
        {
            const v2f xg2 = { v.y, v.y };
            const v2f arg = a2 * xg2;
            const v2f e   = { EXP2(arg.x), EXP2(arg.y) };
            den1 += e; num1 = __builtin_elementwise_fma(e, xg2, num1);
        }
        {
            const v2f xg2 = { v.z, v.z };
            const v2f arg = a2 * xg2;
            const v2f e   = { EXP2(arg.x), EXP2(arg.y) };
            den0 += e; num0 = __builtin_elementwise_fma(e, xg2, num0);
        }
        {
            const v2f xg2 = { v.w, v.w };
            const v2f arg = a2 * xg2;
            const v2f e   = { EXP2(arg.x), EXP2(arg.y) };
            den1 += e; num1 = __builtin_elementwise_fma(e, xg2, num1);
        }
    }
    const v2f den = den0 + den1;
    const v2f num = num0 + num1;
    *(v2f*)&pden[sl][f0] = den;
    *(v2f*)&pnum[sl][f0] = num;
    __syncthreads();

    // Combine 4 slices per f, s_f = num/den, block-sum over 512 f's.
    float sf = 0.0f;
    if (tid < F_DIM) {
        float D = 0.0f, N = 0.0f;
        #pragma unroll
        for (int s = 0; s < 4; ++s) { D += pden[s][tid]; N += pnum[s][tid]; }
        sf = N / D;
    }
    float t = sf;
    for (int o = 32; o > 0; o >>= 1) t += __shfl_down(t, o);
    if (lane == 0 && wave < 8) wsum[wave] = t;
    __syncthreads();

    if (tid < 128) {
        float total = 0.0f;
        #pragma unroll
        for (int i = 0; i < 8; ++i) total += wsum[i];
        out[row * 128 + tid] = total * (1.0f / (float)F_DIM) * wv[tid];
    }
}

extern "C" void kernel_launch(void* const* d_in, const int* in_sizes, int n_in,
                              void* d_out, int out_size, void* d_ws, size_t ws_size,
                              hipStream_t stream) {
    const float* x  = (const float*)d_in[0];  // [8,32,512]
    const float* wq = (const float*)d_in[1];  // [1,128]
    const float* wk = (const float*)d_in[2];  // [1,128]
    const float* wv = (const float*)d_in[3];  // [1,128]
    float* out = (float*)d_out;               // [8,32,128]

    intravol_attn<<<256, 1024, 0, stream>>>(x, wq, wk, wv, out);
}